// Round 5
// baseline (2123.682 us; speedup 1.0000x reference)
//
#include <hip/hip_runtime.h>
#include <math.h>

#define HH 128
#define NPIX 16384
#define BB 8
#define MM 4096
#define NN 16384
#define LRELU_S 0.1f

typedef __attribute__((ext_vector_type(8))) short bf16x8;
typedef __attribute__((ext_vector_type(4))) float f32x4;
typedef __attribute__((address_space(3))) unsigned int as3_u32;
typedef __attribute__((address_space(1))) const unsigned int as1_u32;

__device__ __forceinline__ float leaky_(float v){ return v >= 0.f ? v : LRELU_S*v; }
__device__ __forceinline__ float clamp01(float v){ return fminf(fmaxf(v, 0.f), 1.f); }
__device__ __forceinline__ float clamp02(float v){ return fminf(fmaxf(v, 0.f), 2.f); }
__device__ __forceinline__ unsigned short f2bf(float f){
  unsigned u = __float_as_uint(f);
  u = (u + 0x7FFFu + ((u >> 16) & 1u)) >> 16;
  return (unsigned short)u;
}
__device__ __forceinline__ float bf2f(unsigned short s){
  return __uint_as_float(((unsigned)s) << 16);
}

// ---------- prep: A f32 -> Abf[m][n] bf16 (streaming convert) ----------
__global__ __launch_bounds__(256) void k_prep(const float* __restrict__ A_,
                                              unsigned short* __restrict__ Abf){
  size_t i = ((size_t)blockIdx.x*256 + threadIdx.x)*8;
  float4 v0 = *(const float4*)&A_[i];
  float4 v1 = *(const float4*)&A_[i+4];
  unsigned short o[8] = { f2bf(v0.x), f2bf(v0.y), f2bf(v0.z), f2bf(v0.w),
                          f2bf(v1.x), f2bf(v1.y), f2bf(v1.z), f2bf(v1.w) };
  *(uint4*)&Abf[i] = *(uint4*)o;
}

// ---------- dn[b] = ||d[b,:]|| ----------
__global__ __launch_bounds__(256) void k_dn(const float* __restrict__ d, float* __restrict__ dn){
  int b = blockIdx.x, t = threadIdx.x;
  float ss = 0.f;
  for (int m=t; m<MM; m+=256){ float v = d[b*MM + m]; ss += v*v; }
  #pragma unroll
  for (int off=32; off; off>>=1) ss += __shfl_down(ss, off);
  __shared__ float red[4];
  if ((t & 63) == 0) red[t>>6] = ss;
  __syncthreads();
  if (t == 0) dn[b] = sqrtf(red[0]+red[1]+red[2]+red[3]);
}

// ---------- fused conv chain: x -> rk1 (proven version, unchanged) ----------
__global__ __launch_bounds__(256) void k_conv_chain(const float* __restrict__ x,
    const float* __restrict__ wK, const float* __restrict__ w1, const float* __restrict__ b1,
    const float* __restrict__ w2, const float* __restrict__ b2,
    const float* __restrict__ w3, const float* __restrict__ b3,
    const float* __restrict__ alpha, float* __restrict__ rk){
  __shared__ float xs[24][128];
  __shared__ float bufA[2][22][128];
  __shared__ float bufB[2][18][128];
  __shared__ float wKs[18], w1s[100], w2s[100], w3s[100], bs[3][2];
  __shared__ float twoa;
  int blk = blockIdx.x;              // 128 = 8 b * 16 slabs
  int b = blk >> 4, slab = blk & 15, r0 = slab*8;
  int t = threadIdx.x;
  for (int i=t;i<18;i+=256) wKs[i]=wK[i];
  for (int i=t;i<100;i+=256){ w1s[i]=w1[i]; w2s[i]=w2[i]; w3s[i]=w3[i]; }
  if (t<2){ bs[0][t]=b1[t]; bs[1][t]=b2[t]; bs[2][t]=b3[t]; }
  if (t==0) twoa = 2.f*clamp02(alpha[0]);
  for (int idx=t; idx<24*128; idx+=256){
    int i = idx>>7, j = idx&127, ir = r0-8+i;
    xs[i][j] = ((unsigned)ir < 128u) ? x[b*NPIX + ir*HH + j] : 0.f;
  }
  __syncthreads();
  for (int c=0;c<2;++c)
    for (int idx=t; idx<22*128; idx+=256){
      int i = idx>>7, j = idx&127, ir = r0-7+i;
      float s = 0.f;
      if ((unsigned)ir < 128u){
        #pragma unroll
        for (int di=0;di<3;++di)
          #pragma unroll
          for (int dj=0;dj<3;++dj){
            int jj = j+dj-1;
            if ((unsigned)jj < 128u) s += xs[i+di][jj]*wKs[(c*3+di)*3+dj];
          }
      }
      bufA[c][i][j] = s;
    }
  __syncthreads();
  for (int o=0;o<2;++o)
    for (int idx=t; idx<18*128; idx+=256){
      int i = idx>>7, j = idx&127, ir = r0-5+i;
      float v = 0.f;
      if ((unsigned)ir < 128u){
        float s = bs[0][o];
        #pragma unroll
        for (int c=0;c<2;++c)
          #pragma unroll
          for (int di=0;di<5;++di)
            #pragma unroll
            for (int dj=0;dj<5;++dj){
              int jj = j+dj-2;
              if ((unsigned)jj < 128u) s += bufA[c][i+di][jj]*w1s[(o*2+c)*25+di*5+dj];
            }
        v = bufA[o][i+2][j] + leaky_(s);
      }
      bufB[o][i][j] = v;
    }
  __syncthreads();
  for (int o=0;o<2;++o)
    for (int idx=t; idx<14*128; idx+=256){
      int i = idx>>7, j = idx&127, ir = r0-3+i;
      float v = 0.f;
      if ((unsigned)ir < 128u){
        float s = bs[1][o];
        #pragma unroll
        for (int c=0;c<2;++c)
          #pragma unroll
          for (int di=0;di<5;++di)
            #pragma unroll
            for (int dj=0;dj<5;++dj){
              int jj = j+dj-2;
              if ((unsigned)jj < 128u) s += bufB[c][i+di][jj]*w2s[(o*2+c)*25+di*5+dj];
            }
        v = bufB[o][i+2][j] + leaky_(s);
      }
      bufA[o][i][j] = v;
    }
  __syncthreads();
  for (int o=0;o<2;++o)
    for (int idx=t; idx<10*128; idx+=256){
      int i = idx>>7, j = idx&127, ir = r0-1+i;
      float v = 0.f;
      if ((unsigned)ir < 128u){
        float s = bs[2][o];
        #pragma unroll
        for (int c=0;c<2;++c)
          #pragma unroll
          for (int di=0;di<5;++di)
            #pragma unroll
            for (int dj=0;dj<5;++dj){
              int jj = j+dj-2;
              if ((unsigned)jj < 128u) s += bufA[c][i+di][jj]*w3s[(o*2+c)*25+di*5+dj];
            }
        v = bufA[o][i+2][j] + leaky_(s);
      }
      bufB[o][i][j] = v;
    }
  __syncthreads();
  for (int c=0;c<2;++c)
    for (int idx=t; idx<10*128; idx+=256){
      int i = idx>>7, j = idx&127, ir = r0-1+i;
      float v = 0.f;
      if ((unsigned)ir < 128u){
        float kx = 0.f;
        #pragma unroll
        for (int di=0;di<3;++di)
          #pragma unroll
          for (int dj=0;dj<3;++dj){
            int jj = j+dj-1;
            if ((unsigned)jj < 128u) kx += xs[i+6+di][jj]*wKs[(c*3+di)*3+dj];
          }
        v = twoa*(kx - bufB[c][i][j]);
      }
      bufA[c][i][j] = v;
    }
  __syncthreads();
  for (int idx=t; idx<8*128; idx+=256){
    int i = idx>>7, j = idx&127, ir = r0+i;
    float s = 0.f;
    #pragma unroll
    for (int c=0;c<2;++c)
      #pragma unroll
      for (int di=0;di<3;++di)
        #pragma unroll
        for (int dj=0;dj<3;++dj){
          int jj = j+dj-1;
          if ((unsigned)jj < 128u) s += bufA[c][i+di][jj]*wKs[(c*3+(2-di))*3+(2-dj)];
        }
    rk[b*NPIX + ir*HH + j] = s;
  }
}

// ---------- gemm1s: LDS-staged coalesced MFMA; e[m][16], d2p[mt][8] ----------
// Block: 16 m-rows, 256 thr (4 waves k-split within each 1024-col stage), 16 stages.
// LDS tile layout: byte(row, kb) = row*2048 + (kb ^ ((row&7)<<4))  [src-side swizzle]
__global__ __launch_bounds__(256) void k_gemm1s(const unsigned short* __restrict__ Abf,
    const unsigned short* __restrict__ xtt, const float* __restrict__ d_,
    float* __restrict__ e_, float* __restrict__ d2p){
  __shared__ char tileb[32768];                 // 16 rows x 2048 B
  __shared__ float part[4][16][16];
  __shared__ float p2[16][16];
  int mt = blockIdx.x;                          // 256 blocks
  int m0 = mt*16;
  int t = threadIdx.x;
  int w = t >> 6, lane = t & 63;
  int kg = lane >> 4, col = lane & 15;
  f32x4 acc = {0.f,0.f,0.f,0.f};

  for (int c=0; c<16; ++c){
    if (c) __syncthreads();                     // protect buffer reuse
    // stage: 32 issues of 1 KiB; issue kk covers LDS bytes [kk*1024, +1024)
    #pragma unroll
    for (int q=0; q<8; ++q){
      int kk = w*8 + q;
      int row = kk >> 1;
      int kb = (kk & 1)*1024 + lane*16;
      int cb = kb ^ ((row & 7) << 4);
      const unsigned short* gp = Abf + (size_t)(m0+row)*NN + c*1024 + (cb>>1);
      __builtin_amdgcn_global_load_lds((as1_u32*)gp,
          (as3_u32*)&tileb[kk*1024], 16, 0, 0);
    }
    __syncthreads();                            // compiler drains vmcnt before barrier
    #pragma unroll
    for (int j=0; j<8; ++j){
      int cbyte = w*512 + j*64 + kg*16;
      bf16x8 a = *(const bf16x8*)&tileb[col*2048 + (cbyte ^ ((col & 7) << 4))];
      int nbase = c*1024 + w*256 + j*32;
      bf16x8 b = *(const bf16x8*)(xtt + ((size_t)(nbase>>3) + kg)*128 + col*8);
      acc = __builtin_amdgcn_mfma_f32_16x16x32_bf16(a, b, acc, 0, 0, 0);
    }
  }
  #pragma unroll
  for (int j=0;j<4;++j) part[w][kg*4+j][col] = acc[j];
  __syncthreads();
  {
    int r = t >> 4, b = t & 15;
    float s = part[0][r][b] + part[1][r][b] + part[2][r][b] + part[3][r][b];
    int m = m0 + r;
    float ee = s - ((b < 8) ? d_[b*MM + m] : 0.f);
    e_[m*16 + b] = ee;
    p2[r][b] = (b < 8) ? ee*ee : 0.f;
  }
  __syncthreads();
  if (t < 8){
    float s2 = 0.f;
    #pragma unroll
    for (int r2=0;r2<16;++r2) s2 += p2[r2][t];
    d2p[mt*8 + t] = s2;
  }
}

// ---------- gemm2c: fused proj-coef + A^T z + combine + xtt pack ----------
// Block owns 64 full columns (all 4096 m). 256 blocks x 256 thr.
__global__ __launch_bounds__(256) void k_gemm2c(const unsigned short* __restrict__ Abf,
    const float* __restrict__ e_, const float* __restrict__ d2p,
    const float* __restrict__ dn, const float* __restrict__ delta,
    const float* __restrict__ alpha, const float* __restrict__ beta,
    const float* __restrict__ rk, float* __restrict__ x,
    unsigned short* __restrict__ xtt){
  __shared__ float zs[8][64];
  __shared__ float red8[8][8];
  __shared__ float cf[8];
  __shared__ float redbuf[8][32][16];           // [r][c2][b*2+sub] = 16 KiB
  int blk = blockIdx.x;
  int n0 = blk*64;
  int t = threadIdx.x;
  // cf[b]
  if (t < 64){
    int b = t & 7, prt = t >> 3;
    float s = 0.f;
    for (int i=0;i<32;++i) s += d2p[(prt*32+i)*8 + b];
    red8[prt][b] = s;
  }
  __syncthreads();
  if (t < 8){
    float s2 = 0.f;
    #pragma unroll
    for (int p=0;p<8;++p) s2 += red8[p][t];
    float dist = fmaxf(sqrtf(s2), 1e-10f);
    float de = expf(delta[0]);
    float a = clamp02(alpha[0]);
    cf[t] = 2.f*a*(1.f - fminf(1.f, de*dn[t]/dist));
  }
  __syncthreads();
  int c2 = t & 31, r = t >> 5;
  float acc[8][2];
  #pragma unroll
  for (int b=0;b<8;++b){ acc[b][0]=0.f; acc[b][1]=0.f; }
  for (int mc=0; mc<64; ++mc){
    __syncthreads();
    // stage z chunk: zs[b][rl] = cf[b]*e[mc*64+rl][b]
    {
      int i0 = t*2;
      int b0 = i0>>6, rl0 = i0&63;
      zs[b0][rl0] = cf[b0]*e_[(size_t)(mc*64+rl0)*16 + b0];
      int i1 = i0+1;
      int b1 = i1>>6, rl1 = i1&63;
      zs[b1][rl1] = cf[b1]*e_[(size_t)(mc*64+rl1)*16 + b1];
    }
    __syncthreads();
    #pragma unroll
    for (int rr=0; rr<8; ++rr){
      int rowl = rr*8 + r;
      unsigned a2 = *(const unsigned*)&Abf[(size_t)(mc*64+rowl)*NN + n0 + c2*2];
      float a0 = bf2f((unsigned short)(a2 & 0xffff));
      float a1 = bf2f((unsigned short)(a2 >> 16));
      #pragma unroll
      for (int b=0;b<8;++b){
        float zv = zs[b][rowl];
        acc[b][0] += a0*zv;
        acc[b][1] += a1*zv;
      }
    }
  }
  __syncthreads();
  #pragma unroll
  for (int b=0;b<8;++b){
    redbuf[r][c2][b*2]   = acc[b][0];
    redbuf[r][c2][b*2+1] = acc[b][1];
  }
  __syncthreads();
  float bta = clamp02(beta[0]);
  #pragma unroll
  for (int vv=0; vv<2; ++vv){
    int v = t*2 + vv;                           // 512 outputs: col 0..63 x b 0..7
    int colv = v >> 3, b = v & 7;
    int c2v = colv >> 1, sub = colv & 1;
    float s = 0.f;
    #pragma unroll
    for (int rr=0;rr<8;++rr) s += redbuf[rr][c2v][b*2+sub];
    int pix = n0 + colv;
    float xn = clamp01(x[b*NPIX + pix] - bta*(rk[b*NPIX + pix] + s));
    x[b*NPIX + pix] = xn;
    xtt[((size_t)(pix>>3)*16 + b)*8 + (pix&7)] = f2bf(xn);
  }
}

extern "C" void kernel_launch(void* const* d_in, const int* in_sizes, int n_in,
                              void* d_out, int out_size, void* d_ws, size_t ws_size,
                              hipStream_t stream) {
  const float* d_d   = (const float*)d_in[0];
  const float* d_A   = (const float*)d_in[1];
  const float* w1    = (const float*)d_in[2];
  const float* b1    = (const float*)d_in[3];
  const float* w2    = (const float*)d_in[4];
  const float* b2    = (const float*)d_in[5];
  const float* w3    = (const float*)d_in[6];
  const float* b3    = (const float*)d_in[7];
  const float* wK    = (const float*)d_in[8];
  const float* delta = (const float*)d_in[9];
  const float* alpha = (const float*)d_in[10];
  const float* beta  = (const float*)d_in[12];

  char* p = (char*)d_ws;
  unsigned short* Abf = (unsigned short*)p; p += (size_t)MM*NN*2;      // 128 MiB
  unsigned short* xtt = (unsigned short*)p; p += (size_t)2048*16*8*2;  // 512 KiB
  float* x   = (float*)p; p += (size_t)BB*NPIX*4;
  float* rk1 = (float*)p; p += (size_t)BB*NPIX*4;
  float* e_  = (float*)p; p += (size_t)MM*16*4;                        // 256 KiB
  float* d2p = (float*)p; p += (size_t)256*8*4;
  float* dnb = (float*)p; p += 64;

  k_prep<<<MM*NN/(256*8), 256, 0, stream>>>(d_A, Abf);
  k_dn<<<BB, 256, 0, stream>>>(d_d, dnb);
  hipMemsetAsync(x, 0, (size_t)BB*NPIX*4, stream);
  hipMemsetAsync(xtt, 0, (size_t)2048*16*8*2, stream);

  for (int it=0; it<9; ++it){
    k_conv_chain<<<128, 256, 0, stream>>>(x, wK, w1, b1, w2, b2, w3, b3, alpha, rk1);
    k_gemm1s<<<256, 256, 0, stream>>>(Abf, xtt, d_d, e_, d2p);
    k_gemm2c<<<256, 256, 0, stream>>>(Abf, e_, d2p, dnb, delta, alpha, beta, rk1, x, xtt);
  }

  hipMemcpyAsync(d_out, x, (size_t)BB*NPIX*4, hipMemcpyDeviceToDevice, stream);
}